// Round 11
// baseline (441.186 us; speedup 1.0000x reference)
//
#include <hip/hip_runtime.h>
#include <math.h>

// Persistent-GRU rollout for MI355X. B=32, H=48, T=16, F=256, L=2, S=64, A=16, R=8.
// R11: 32 groups x 8 WGs, ONE batch per group (gid = batch). Each WG owns 64
// features (192 gate rows) of one layer; weights register-resident: thread
// (jp=tid>>2, ks=tid&3) holds 3 rows x 128-K chunk = 384 VGPRs. Fan-in per
// h-vector = 4 producer WGs (was 16) -> straggler-max and poll traffic cut.
// Sync = R8's write-once sentinel data-poll (poll IS the data load, no extra
// hops, no barriers); 64 lanes/WG poll 16B each with backoff after 32 spins.

#define BLK 256

// LDS float offsets
#define O_XQ    0       // 2 chunks x 132 (x, 256 floats padded)
#define O_HQ    264     // h_prev
#define O_H1Q   528     // h1 (heads input)
#define O_PART  792     // 192 rows x 8 (4 partials + pad)
#define O_SST   2328    // 64 (s / present_s staging)
#define O_BI    2392    // 192
#define O_BH    2584    // 192
#define O_BSO   2776    // 64
#define O_BR    2840    // 8
#define O_WST   2848    // Wso TRANSPOSED: [k]*65 + so (256*65 = 16640, conflict-free)
#define O_WRF   19488   // Wr row-major 8 x 260
#define LDS_FLOATS 21568
#define LDS_BYTES  (LDS_FLOATS * 4)   // 86.3KB -> 1 WG/CU

// workspace float-region (= d_ws); all poisoned 0x7F7F7F7F each launch
#define O_SEQ  0        // [batch][t][f] 32*48*256 = 393216 (write-once)
#define O_H0R  393216   // 64 slots x 32*256 (write-once, slot = u)
#define O_H1R  917504
#define WS_FLOATS 1441792
#define POISON_BYTES (WS_FLOATS * 4)   // 5.77 MB

using vf4 = __attribute__((ext_vector_type(4))) float;

__device__ __forceinline__ float dotv(vf4 a, vf4 b, float acc) {
  acc = fmaf(a[0], b[0], acc); acc = fmaf(a[1], b[1], acc);
  acc = fmaf(a[2], b[2], acc); acc = fmaf(a[3], b[3], acc);
  return acc;
}

// sentinel 0x7F7F7F7F ~ 3.4e38; all real published values are |v| <= 1
__device__ __forceinline__ bool valid4(vf4 v) {
  return fabsf(v[0]) < 1.0e30f && fabsf(v[1]) < 1.0e30f &&
         fabsf(v[2]) < 1.0e30f && fabsf(v[3]) < 1.0e30f;
}

// LLC-coherent accesses (sc0 sc1: bypass L1+L2, coherent device-wide)
__device__ __forceinline__ void llc_issue4(vf4& v, const float* p) {
  asm volatile("global_load_dwordx4 %0, %1, off sc0 sc1"
               : "=&v"(v) : "v"(p) : "memory");
}
__device__ __forceinline__ void llc_storef(float* p, float v) {
  asm volatile("global_store_dword %0, %1, off sc0 sc1" :: "v"(p), "v"(v) : "memory");
}
__device__ __forceinline__ void vwait() {
  asm volatile("s_waitcnt vmcnt(0)" ::: "memory");
  __builtin_amdgcn_sched_barrier(0);
}

extern "C" __global__ void __launch_bounds__(BLK, 1)
gru_rollout_kernel(const float* __restrict__ hist_s,
                   const float* __restrict__ hist_a,
                   const float* __restrict__ present_s,
                   const float* __restrict__ future_a,
                   const float* __restrict__ Ws, const float* __restrict__ bs,
                   const float* __restrict__ Wa, const float* __restrict__ ba,
                   const float* __restrict__ Wih, const float* __restrict__ Whh,
                   const float* __restrict__ bih, const float* __restrict__ bhh,
                   const float* __restrict__ Wr, const float* __restrict__ br,
                   const float* __restrict__ Wso, const float* __restrict__ bso,
                   float* __restrict__ out, float* __restrict__ wsf)
{
  extern __shared__ float lds[];
  float* XQ   = lds + O_XQ;
  float* HQ   = lds + O_HQ;
  float* H1Q  = lds + O_H1Q;
  float* PART = lds + O_PART;
  float* SST  = lds + O_SST;
  float* BI   = lds + O_BI;
  float* BH   = lds + O_BH;
  float* BSO  = lds + O_BSO;
  float* BR   = lds + O_BR;
  float* WST  = lds + O_WST;
  float* WRF  = lds + O_WRF;

  const int tid = threadIdx.x;
  const int bid = blockIdx.x;
  const int gid = bid & 31;       // group == batch (members share XCD: bid%8 const)
  const int mem = bid >> 5;       // member 0..7
  const bool isL0 = (mem < 4);
  const int fc = mem & 3;         // feature chunk: [64fc, 64fc+64)
  const int layer = isL0 ? 0 : 1;

  const int jp = tid >> 2;        // row-triple 0..63 (rows {jp, 64+jp, 128+jp})
  const int ks = tid & 3;         // K-chunk 0..3 (128 wide; 0,1=Wih 2,3=Whh)

  float* seq = wsf + O_SEQ;
  float* h0r = wsf + O_H0R;
  float* h1r = wsf + O_H1R;

  // staging lane map (tid<64): lane covers 16B of the 1KB h/x vector
  const int lane = tid;                       // valid when tid<64
  const int goff = lane * 4;
  const int loff = (lane >> 5) * 132 + (lane & 31) * 4;
  const int gvec = gid * 256 + goff;          // offset within a 32x256 slot

  // data-polls (lanes<64 only; the successful poll IS the data load)
  auto pollA = [&](float* d, const float* p) {
    vf4 v; int g = 0;
    for (;;) {
      llc_issue4(v, p); vwait();
      if (valid4(v)) break;
      if (++g > 32) __builtin_amdgcn_s_sleep(1);
      if (g > (1 << 18)) break;   // failsafe
    }
    *(vf4*)d = v;
  };
  auto pollB = [&](float* d1, const float* p1, float* d2, const float* p2) {
    vf4 v1, v2; int g = 0;
    for (;;) {
      llc_issue4(v1, p1); llc_issue4(v2, p2); vwait();
      if (valid4(v1) && valid4(v2)) break;
      if (++g > 32) __builtin_amdgcn_s_sleep(1);
      if (g > (1 << 18)) break;   // failsafe
    }
    *(vf4*)d1 = v1; *(vf4*)d2 = v2;
  };
  auto zeroH = [&](float* d) { *(vf4*)d = (vf4){0.f, 0.f, 0.f, 0.f}; };

  // register-resident weights: rows {jp, 64+jp, 128+jp}, K-chunk ks (128 wide)
  vf4 w[3][32];
  {
    const float* src = (ks < 2) ? Wih : Whh;
    const int cb = (ks & 1) * 128;
    #pragma unroll
    for (int r = 0; r < 3; ++r) {
      int grow = layer * 768 + r * 256 + fc * 64 + jp;
      const float* wr = src + grow * 256 + cb;
      #pragma unroll
      for (int c = 0; c < 32; ++c) w[r][c] = *(const vf4*)(wr + c * 4);
    }
  }
  const float* xb = (ks < 2) ? (XQ + ks * 132) : (HQ + (ks - 2) * 132);

  // GRU cell: reg-weight FMA -> PART -> gate reduce (1 wave) -> LLC store
  auto cell = [&](float* dst) {
    __syncthreads();   // staging/XQ visible
    float a0 = 0.f, a1 = 0.f, a2 = 0.f;
    const vf4* xp = (const vf4*)xb;
    #pragma unroll
    for (int c4 = 0; c4 < 8; ++c4) {
      vf4 x0 = xp[c4 * 4 + 0], x1 = xp[c4 * 4 + 1];
      vf4 x2 = xp[c4 * 4 + 2], x3 = xp[c4 * 4 + 3];
      a0 = dotv(w[0][c4 * 4 + 0], x0, a0); a0 = dotv(w[0][c4 * 4 + 1], x1, a0);
      a0 = dotv(w[0][c4 * 4 + 2], x2, a0); a0 = dotv(w[0][c4 * 4 + 3], x3, a0);
      a1 = dotv(w[1][c4 * 4 + 0], x0, a1); a1 = dotv(w[1][c4 * 4 + 1], x1, a1);
      a1 = dotv(w[1][c4 * 4 + 2], x2, a1); a1 = dotv(w[1][c4 * 4 + 3], x3, a1);
      a2 = dotv(w[2][c4 * 4 + 0], x0, a2); a2 = dotv(w[2][c4 * 4 + 1], x1, a2);
      a2 = dotv(w[2][c4 * 4 + 2], x2, a2); a2 = dotv(w[2][c4 * 4 + 3], x3, a2);
    }
    PART[jp * 8 + ks] = a0;            // r-gate row jp
    PART[(64 + jp) * 8 + ks] = a1;     // z
    PART[(128 + jp) * 8 + ks] = a2;    // n
    __syncthreads();
    if (tid < 64) {
      int i = tid;
      vf4 p0 = *(const vf4*)(PART + i * 8);
      vf4 p1 = *(const vf4*)(PART + (64 + i) * 8);
      vf4 p2 = *(const vf4*)(PART + (128 + i) * 8);
      float pr = (p0[0] + p0[1]) + (p0[2] + p0[3]) + BI[i] + BH[i];
      float pz = (p1[0] + p1[1]) + (p1[2] + p1[3]) + BI[64 + i] + BH[64 + i];
      float xn = p2[0] + p2[1] + BI[128 + i];      // ks 0,1 = Wih part
      float hn = p2[2] + p2[3] + BH[128 + i];      // ks 2,3 = Whh part
      float rg = 1.f / (1.f + expf(-pr));
      float zg = 1.f / (1.f + expf(-pz));
      float ng = tanhf(xn + rg * hn);
      int f = fc * 64 + i;
      float hp = HQ[(f >> 7) * 132 + (f & 127)];
      llc_storef(dst + gid * 256 + f, (1.f - zg) * ng + zg * hp);
    }
  };

  // heads for rollout step tt (requires H1Q staged+synced). All L0 WGs fill
  // SST (needed by xdot); WG mem==0 writes future_s / future_r.
  auto heads = [&](int tt) {
    if (tid < 64) {
      int so = tid;
      float a = BSO[so];
      #pragma unroll 16
      for (int k = 0; k < 256; ++k)
        a = fmaf(WST[k * 65 + so], H1Q[(k >> 7) * 132 + (k & 127)], a);
      float sv = tanhf(a);
      SST[so] = sv;
      if (mem == 0) out[4096 + (gid * 16 + tt) * 64 + so] = sv;   // future_s
    }
    if (mem == 0 && tid >= 64 && tid < 72) {
      int q = tid - 64;
      const vf4* wrow = (const vf4*)(WRF + q * 260);
      const vf4* h0c = (const vf4*)(H1Q);
      const vf4* h1c = (const vf4*)(H1Q + 132);
      float a = BR[q];
      #pragma unroll
      for (int c = 0; c < 32; ++c) a = dotv(wrow[c], h0c[c], a);
      #pragma unroll
      for (int c = 0; c < 32; ++c) a = dotv(wrow[32 + c], h1c[c], a);
      out[(gid * 16 + tt) * 8 + q] = tanhf(a);                    // future_r
    }
  };

  // x_t = tanh(Ws@SST + bs + Wa@fa_t + ba) -> XQ (256 features, 1 batch)
  auto xdot = [&](int t) {
    const int f = tid;
    const vf4* wsr = (const vf4*)(Ws + f * 64);
    float a = bs[f] + ba[f];
    #pragma unroll
    for (int c = 0; c < 16; ++c)
      a = dotv(wsr[c], *(const vf4*)(SST + c * 4), a);
    const vf4* war = (const vf4*)(Wa + f * 16);
    const vf4* fa = (const vf4*)(future_a + (gid * 16 + t) * 16);
    a = dotv(war[0], fa[0], a); a = dotv(war[1], fa[1], a);
    a = dotv(war[2], fa[2], a); a = dotv(war[3], fa[3], a);
    XQ[(f >> 7) * 132 + (f & 127)] = tanhf(a);
  };

  // ---------------- prologue ----------------
  if (tid < 192) {
    int r = tid >> 6, i = tid & 63;
    int grow = layer * 768 + r * 256 + fc * 64 + i;
    BI[tid] = bih[grow];
    BH[tid] = bhh[grow];
  }
  if (isL0) {
    for (int idx = tid; idx < 64 * 256; idx += BLK) {   // Wso -> transposed LDS
      int so = idx >> 8, k = idx & 255;
      WST[k * 65 + so] = Wso[so * 256 + k];
    }
    for (int idx = tid; idx < 8 * 256; idx += BLK) {
      int r = idx >> 8, k = idx & 255;
      WRF[r * 260 + k] = Wr[r * 256 + k];
    }
    if (tid < 64) BSO[tid] = bso[tid];
    if (tid < 8)  BR[tid] = br[tid];
  }
  // seq = tanh(embed(history)) for this group's batch; split over 8 WGs
  for (int e = mem * 1536 + tid; e < mem * 1536 + 1536; e += BLK) {
    int t = e >> 8, f = e & 255;
    const float* hs = hist_s + (gid * 48 + t) * 64;
    const float* ha = hist_a + (gid * 48 + t) * 16;
    const float* wsr = Ws + f * 64;
    const float* war = Wa + f * 16;
    float a = bs[f] + ba[f];
    for (int k = 0; k < 64; ++k) a = fmaf(wsr[k], hs[k], a);
    for (int k = 0; k < 16; ++k) a = fmaf(war[k], ha[k], a);
    llc_storef(&seq[(gid * 48 + t) * 256 + f], tanhf(a));
  }
  __syncthreads();

  // ------------- unified loop: u = 0..63 (48 history + 16 rollout) -----------
  for (int u = 0; u < 64; ++u) {
    if (isL0) {
      if (u < 48) {
        if (tid < 64) {
          if (u == 0) {
            pollA(XQ + loff, seq + (gid * 48) * 256 + goff);
            zeroH(HQ + loff);
          } else {
            pollB(XQ + loff, seq + (gid * 48 + u) * 256 + goff,
                  HQ + loff, h0r + (u - 1) * 8192 + gvec);
          }
        }
        cell(h0r + u * 8192);
      } else {
        const int t = u - 48;
        if (t == 0) {
          if (tid < 64) {
            SST[tid] = present_s[gid * 64 + tid];
            pollA(HQ + loff, h0r + 47 * 8192 + gvec);
          }
          __syncthreads();
        } else {
          if (tid < 64)
            pollB(HQ + loff,  h0r + (u - 1) * 8192 + gvec,
                  H1Q + loff, h1r + (u - 1) * 8192 + gvec);
          __syncthreads();
          heads(t - 1);
          __syncthreads();
        }
        xdot(t);
        cell(h0r + u * 8192);
      }
    } else {
      if (tid < 64) {
        if (u == 0) {
          pollA(XQ + loff, h0r + gvec);
          zeroH(HQ + loff);
        } else {
          pollB(XQ + loff, h0r + u * 8192 + gvec,
                HQ + loff, h1r + (u - 1) * 8192 + gvec);
        }
      }
      cell(h1r + u * 8192);
    }
  }

  // tail heads for t=15 (mem==0 WG reads h1[63])
  if (isL0 && mem == 0) {
    if (tid < 64) pollA(H1Q + loff, h1r + 63 * 8192 + gvec);
    __syncthreads();
    heads(15);
  }
}

extern "C" void kernel_launch(void* const* d_in, const int* in_sizes, int n_in,
                              void* d_out, int out_size, void* d_ws, size_t ws_size,
                              hipStream_t stream) {
  (void)in_sizes; (void)n_in; (void)out_size; (void)ws_size;
  const float* hist_s    = (const float*)d_in[0];
  const float* hist_a    = (const float*)d_in[1];
  const float* present_s = (const float*)d_in[2];
  const float* future_a  = (const float*)d_in[3];
  const float* Ws  = (const float*)d_in[4];
  const float* bs  = (const float*)d_in[5];
  const float* Wa  = (const float*)d_in[6];
  const float* ba  = (const float*)d_in[7];
  const float* Wih = (const float*)d_in[8];
  const float* Whh = (const float*)d_in[9];
  const float* bih = (const float*)d_in[10];
  const float* bhh = (const float*)d_in[11];
  const float* Wr  = (const float*)d_in[12];
  const float* br  = (const float*)d_in[13];
  const float* Wso = (const float*)d_in[14];
  const float* bso = (const float*)d_in[15];
  float* out = (float*)d_out;
  float* wsf = (float*)d_ws;

  // poison all cross-WG buffers to sentinel each launch (write-once discipline)
  hipMemsetAsync(d_ws, 0x7F, POISON_BYTES, stream);
  hipFuncSetAttribute(reinterpret_cast<const void*>(gru_rollout_kernel),
                      hipFuncAttributeMaxDynamicSharedMemorySize, LDS_BYTES);
  hipLaunchKernelGGL(gru_rollout_kernel, dim3(256), dim3(BLK), LDS_BYTES, stream,
                     hist_s, hist_a, present_s, future_a,
                     Ws, bs, Wa, ba, Wih, Whh, bih, bhh, Wr, br, Wso, bso,
                     out, wsf);
}

// Round 13
// 349.154 us; speedup vs baseline: 1.2636x; 1.2636x over previous
//
#include <hip/hip_runtime.h>
#include <math.h>

// Persistent-GRU rollout for MI355X. B=32, H=48, T=16, F=256, L=2, S=64, A=16, R=8.
// 8 groups x 32 WGs; gid = blockIdx%8. Each WG owns 48 gate-rows of one layer,
// weights register-resident. R13 = R8 (write-once sentinel data-poll, no
// barriers, single sc0sc1 stores/polls) + LLC WARM-UP, crash-fixed vs R12:
// the six touch-loads and their s_waitcnt are fused into ONE asm block so the
// dest VGPRs stay reserved until the loads complete (R12 issued them in
// separate blocks with dead outputs -> compiler reallocated the regs -> async
// writeback clobbered live registers -> GPU memory fault).

#define BLK 256
#define CH  36          // padded floats per 32-chunk
#define BST 292         // 8*CH + 4

// LDS float offsets
#define O_XQ    0       // 4*292 chunked x
#define O_HQ    1168    // 4*292 chunked h_prev
#define O_H1Q   2336    // 4*292 chunked h1 (heads input)
#define O_PART  3504    // 48*68 partials [j][b*16+ks]
#define O_SST   6768    // 4*64 s / present_s staging
#define O_BI    7024    // 48
#define O_BH    7072    // 48
#define O_BSO   7120    // 64
#define O_BR    7184    // 8
#define O_WSOF  7200    // 64*260 full Wso (L0 WGs)
#define O_WRF   23840   // 8*260 full Wr
#define LDS_FLOATS 25920
#define LDS_BYTES  (LDS_FLOATS * 4)   // 103.7KB -> 1 WG/CU

// workspace float-region (= d_ws); all poisoned 0x7F7F7F7F each launch
#define O_SEQ  0        // 32*48*256 = 393216 (write-once)
#define O_H0R  393216   // 64 slots x 32*256 = 524288 (write-once, slot = u)
#define O_H1R  917504   // 524288
#define WS_FLOATS 1441792
#define POISON_BYTES (WS_FLOATS * 4)   // 5.77 MB

using vf4 = __attribute__((ext_vector_type(4))) float;

__device__ __forceinline__ float dotv(vf4 a, vf4 b, float acc) {
  acc = fmaf(a[0], b[0], acc); acc = fmaf(a[1], b[1], acc);
  acc = fmaf(a[2], b[2], acc); acc = fmaf(a[3], b[3], acc);
  return acc;
}
__device__ __forceinline__ float hsum(vf4 v) { return (v[0]+v[1]) + (v[2]+v[3]); }

// sentinel = 0x7F7F7F7F ~ 3.4e38; every real value here is tanh/blend, |v| <= 1
__device__ __forceinline__ bool valid4(vf4 v) {
  return fabsf(v[0]) < 1.0e30f && fabsf(v[1]) < 1.0e30f &&
         fabsf(v[2]) < 1.0e30f && fabsf(v[3]) < 1.0e30f;
}

// --- LLC-coherent accesses (sc0 sc1: bypass L1+L2, coherent device-wide) ---
__device__ __forceinline__ void llc_issue4(vf4& v, const float* p) {
  asm volatile("global_load_dwordx4 %0, %1, off sc0 sc1"
               : "=&v"(v) : "v"(p) : "memory");
}
__device__ __forceinline__ void llc_storef(float* p, float v) {
  asm volatile("global_store_dword %0, %1, off sc0 sc1" :: "v"(p), "v"(v) : "memory");
}
__device__ __forceinline__ void vwait() {
  asm volatile("s_waitcnt vmcnt(0)" ::: "memory");
  __builtin_amdgcn_sched_barrier(0);
}

extern "C" __global__ void __launch_bounds__(BLK, 1)
gru_rollout_kernel(const float* __restrict__ hist_s,
                   const float* __restrict__ hist_a,
                   const float* __restrict__ present_s,
                   const float* __restrict__ future_a,
                   const float* __restrict__ Ws, const float* __restrict__ bs,
                   const float* __restrict__ Wa, const float* __restrict__ ba,
                   const float* __restrict__ Wih, const float* __restrict__ Whh,
                   const float* __restrict__ bih, const float* __restrict__ bhh,
                   const float* __restrict__ Wr, const float* __restrict__ br,
                   const float* __restrict__ Wso, const float* __restrict__ bso,
                   float* __restrict__ out, float* __restrict__ wsf)
{
  extern __shared__ float lds[];
  float* XQ   = lds + O_XQ;
  float* HQ   = lds + O_HQ;
  float* H1Q  = lds + O_H1Q;
  float* PART = lds + O_PART;
  float* SST  = lds + O_SST;
  float* BI   = lds + O_BI;
  float* BH   = lds + O_BH;
  float* BSO  = lds + O_BSO;
  float* BR   = lds + O_BR;
  float* WSOF = lds + O_WSOF;
  float* WRF  = lds + O_WRF;

  const int tid = threadIdx.x;
  const int bid = blockIdx.x;
  const int gid = bid & 7;
  const int mem = bid >> 3;
  const bool isL0 = (mem < 16);
  const int fc = mem & 15;
  const int layer = isL0 ? 0 : 1;

  const int jp = tid >> 4;        // row-triple 0..15
  const int ks = tid & 15;        // K-chunk 0..15

  float* seq = wsf + O_SEQ;
  float* h0r = wsf + O_H0R;
  float* h1r = wsf + O_H1R;

  // staging lane mapping (chunked, conflict-free)
  const int sb = tid >> 6, srem = tid & 63;
  const int sko = srem >> 3, ssl = srem & 7;
  const int goff = sko * 32 + ssl * 4;
  const int loff = sb * BST + sko * CH + ssl * 4;
  const int gvec = (gid * 4 + sb) * 256 + goff;   // lane offset in a 32x256 slot

  // sentinel polls: loop until all words are real values; the poll IS the load
  auto poll1 = [&](float* d, const float* p) {
    vf4 v; int g = 0;
    for (;;) {
      llc_issue4(v, p); vwait();
      if (valid4(v) || ++g > (1 << 18)) break;
    }
    *(vf4*)d = v;
  };
  auto poll2 = [&](float* d1, const float* p1, float* d2, const float* p2) {
    vf4 v1, v2; int g = 0;
    for (;;) {
      llc_issue4(v1, p1); llc_issue4(v2, p2); vwait();
      if ((valid4(v1) && valid4(v2)) || ++g > (1 << 18)) break;
    }
    *(vf4*)d1 = v1; *(vf4*)d2 = v2;
  };
  auto zeroH = [&](float* d) { *(vf4*)d = (vf4){0.f, 0.f, 0.f, 0.f}; };

  // register-resident weights: rows 3jp..3jp+2, chunk ks
  vf4 w[3][8];
  {
    const float* src = (ks < 8) ? Wih : Whh;
    const int cb = (ks & 7) * 32;
    #pragma unroll
    for (int r = 0; r < 3; ++r) {
      int j = jp * 3 + r;
      int grow = (layer * 768) + (j >> 4) * 256 + fc * 16 + (j & 15);
      const float* wr = src + grow * 256 + cb;
      #pragma unroll
      for (int c = 0; c < 8; ++c) w[r][c] = *(const vf4*)(wr + c * 4);
    }
  }
  const float* xq_base = (ks < 8) ? (XQ + ks * CH) : (HQ + (ks - 8) * CH);

  // GRU cell: FMA on reg weights -> PART -> single-sync gate reduce -> store
  auto cell = [&](float* dst) {
    __syncthreads();   // staging/XQ visible
    float a0[4], a1[4], a2[4];
    #pragma unroll
    for (int b = 0; b < 4; ++b) { a0[b] = 0.f; a1[b] = 0.f; a2[b] = 0.f; }
    #pragma unroll
    for (int b = 0; b < 4; ++b) {
      const vf4* xb = (const vf4*)(xq_base + b * BST);
      vf4 x0 = xb[0], x1 = xb[1], x2 = xb[2], x3 = xb[3];
      vf4 x4 = xb[4], x5 = xb[5], x6 = xb[6], x7 = xb[7];
      float a = a0[b];
      a = dotv(w[0][0], x0, a); a = dotv(w[0][1], x1, a);
      a = dotv(w[0][2], x2, a); a = dotv(w[0][3], x3, a);
      a = dotv(w[0][4], x4, a); a = dotv(w[0][5], x5, a);
      a = dotv(w[0][6], x6, a); a = dotv(w[0][7], x7, a);
      a0[b] = a; a = a1[b];
      a = dotv(w[1][0], x0, a); a = dotv(w[1][1], x1, a);
      a = dotv(w[1][2], x2, a); a = dotv(w[1][3], x3, a);
      a = dotv(w[1][4], x4, a); a = dotv(w[1][5], x5, a);
      a = dotv(w[1][6], x6, a); a = dotv(w[1][7], x7, a);
      a1[b] = a; a = a2[b];
      a = dotv(w[2][0], x0, a); a = dotv(w[2][1], x1, a);
      a = dotv(w[2][2], x2, a); a = dotv(w[2][3], x3, a);
      a = dotv(w[2][4], x4, a); a = dotv(w[2][5], x5, a);
      a = dotv(w[2][6], x6, a); a = dotv(w[2][7], x7, a);
      a2[b] = a;
    }
    #pragma unroll
    for (int b = 0; b < 4; ++b) {
      PART[(jp * 3 + 0) * 68 + b * 16 + ks] = a0[b];
      PART[(jp * 3 + 1) * 68 + b * 16 + ks] = a1[b];
      PART[(jp * 3 + 2) * 68 + b * 16 + ks] = a2[b];
    }
    __syncthreads();
    if (tid < 64) {
      int i = tid >> 2, b = tid & 3;
      const vf4* pr4 = (const vf4*)(PART + i * 68 + b * 16);
      const vf4* pz4 = (const vf4*)(PART + (16 + i) * 68 + b * 16);
      const vf4* pn4 = (const vf4*)(PART + (32 + i) * 68 + b * 16);
      float pr = hsum(pr4[0]) + hsum(pr4[1]) + hsum(pr4[2]) + hsum(pr4[3])
               + BI[i] + BH[i];
      float pz = hsum(pz4[0]) + hsum(pz4[1]) + hsum(pz4[2]) + hsum(pz4[3])
               + BI[16 + i] + BH[16 + i];
      float xn = hsum(pn4[0]) + hsum(pn4[1]) + BI[32 + i];
      float hn = hsum(pn4[2]) + hsum(pn4[3]) + BH[32 + i];
      float rg = 1.f / (1.f + expf(-pr));
      float zg = 1.f / (1.f + expf(-pz));
      float ng = tanhf(xn + rg * hn);
      int f = fc * 16 + i;
      float hp = HQ[b * BST + (f >> 5) * CH + (f & 31)];
      llc_storef(dst + (gid * 4 + b) * 256 + f, (1.f - zg) * ng + zg * hp);
    }
  };

  // heads for rollout step tt: s -> SST (all L0 WGs); out r/s by mem==0 only
  auto heads = [&](int tt) {
    int so = tid >> 2, b = tid & 3;
    const vf4* wrow = (const vf4*)(WSOF + so * 260);
    float a = BSO[so];
    #pragma unroll
    for (int ko = 0; ko < 8; ++ko) {
      const vf4* hv = (const vf4*)(H1Q + b * BST + ko * CH);
      a = dotv(wrow[ko * 8 + 0], hv[0], a); a = dotv(wrow[ko * 8 + 1], hv[1], a);
      a = dotv(wrow[ko * 8 + 2], hv[2], a); a = dotv(wrow[ko * 8 + 3], hv[3], a);
      a = dotv(wrow[ko * 8 + 4], hv[4], a); a = dotv(wrow[ko * 8 + 5], hv[5], a);
      a = dotv(wrow[ko * 8 + 6], hv[6], a); a = dotv(wrow[ko * 8 + 7], hv[7], a);
    }
    float sv = tanhf(a);
    SST[b * 64 + so] = sv;
    if (mem == 0) {
      out[4096 + ((gid * 4 + b) * 16 + tt) * 64 + so] = sv;   // future_s
      if (tid < 32) {
        int q = tid >> 2;
        const vf4* wr2 = (const vf4*)(WRF + q * 260);
        float ar = BR[q];
        #pragma unroll
        for (int ko = 0; ko < 8; ++ko) {
          const vf4* hv = (const vf4*)(H1Q + b * BST + ko * CH);
          #pragma unroll
          for (int c = 0; c < 8; ++c) ar = dotv(wr2[ko * 8 + c], hv[c], ar);
        }
        out[((gid * 4 + b) * 16 + tt) * 8 + q] = tanhf(ar);   // future_r
      }
    }
  };

  // x_t = tanh(Ws@SST + bs + Wa@fa_t + ba) -> XQ (all 256 features per WG)
  auto xdot = [&](int t) {
    const int f = tid;
    float a0 = bs[f], a1 = a0, a2 = a0, a3 = a0;
    const vf4* wsr = (const vf4*)(Ws + f * 64);
    #pragma unroll 4
    for (int c = 0; c < 16; ++c) {
      vf4 wv = wsr[c];
      a0 = dotv(wv, *(const vf4*)(SST + 0 * 64 + c * 4), a0);
      a1 = dotv(wv, *(const vf4*)(SST + 1 * 64 + c * 4), a1);
      a2 = dotv(wv, *(const vf4*)(SST + 2 * 64 + c * 4), a2);
      a3 = dotv(wv, *(const vf4*)(SST + 3 * 64 + c * 4), a3);
    }
    const vf4* war = (const vf4*)(Wa + f * 16);
    vf4 w0 = war[0], w1 = war[1], w2 = war[2], w3 = war[3];
    float x4[4] = {a0, a1, a2, a3};
    #pragma unroll
    for (int b = 0; b < 4; ++b) {
      const vf4* fa = (const vf4*)(future_a + ((gid * 4 + b) * 16 + t) * 16);
      float a = ba[f] + x4[b];
      a = dotv(w0, fa[0], a); a = dotv(w1, fa[1], a);
      a = dotv(w2, fa[2], a); a = dotv(w3, fa[3], a);
      XQ[b * BST + (f >> 5) * CH + (f & 31)] = tanhf(a);
    }
  };

  // ---------------- prologue: LDS fills + LLC warm-up + seq ----------------
  if (tid < 48) {
    int g = tid >> 4, i = tid & 15;
    int grow = layer * 768 + g * 256 + fc * 16 + i;
    BI[tid] = bih[grow];
    BH[tid] = bhh[grow];
  }
  if (isL0) {
    for (int idx = tid; idx < 64 * 256; idx += BLK) {
      int r = idx >> 8, k = idx & 255;
      WSOF[r * 260 + k] = Wso[r * 256 + k];
    }
    for (int idx = tid; idx < 8 * 256; idx += BLK) {
      int r = idx >> 8, k = idx & 255;
      WRF[r * 260 + k] = Wr[r * 256 + k];
    }
    if (tid < 64) BSO[tid] = bso[tid];
    if (tid < 8)  BR[tid] = br[tid];
  }
  // LLC warm-up: touch every 16B of the ws region so all poll lines are
  // LLC-resident. SINGLE asm block (loads + waitcnt together) -> dest regs
  // reserved until completion; addresses pre-clamped (no conditionals).
  {
    const int nvec = WS_FLOATS / 4;            // 360448 16B-vectors
    int i0 = bid * BLK + tid;
    int i1 = i0 + 65536, i2 = i1 + 65536, i3 = i2 + 65536;
    int i4 = i3 + 65536, i5 = i4 + 65536;
    const float* p0 = wsf + (size_t)(i0 < nvec ? i0 : 0) * 4;
    const float* p1 = wsf + (size_t)(i1 < nvec ? i1 : 0) * 4;
    const float* p2 = wsf + (size_t)(i2 < nvec ? i2 : 0) * 4;
    const float* p3 = wsf + (size_t)(i3 < nvec ? i3 : 0) * 4;
    const float* p4 = wsf + (size_t)(i4 < nvec ? i4 : 0) * 4;
    const float* p5 = wsf + (size_t)(i5 < nvec ? i5 : 0) * 4;
    vf4 t0, t1, t2, t3, t4, t5;
    asm volatile(
      "global_load_dwordx4 %0, %6, off sc0 sc1\n\t"
      "global_load_dwordx4 %1, %7, off sc0 sc1\n\t"
      "global_load_dwordx4 %2, %8, off sc0 sc1\n\t"
      "global_load_dwordx4 %3, %9, off sc0 sc1\n\t"
      "global_load_dwordx4 %4, %10, off sc0 sc1\n\t"
      "global_load_dwordx4 %5, %11, off sc0 sc1\n\t"
      "s_waitcnt vmcnt(0)"
      : "=&v"(t0), "=&v"(t1), "=&v"(t2), "=&v"(t3), "=&v"(t4), "=&v"(t5)
      : "v"(p0), "v"(p1), "v"(p2), "v"(p3), "v"(p4), "v"(p5)
      : "memory");
  }
  // seq = tanh(embed(history)), split over the group's 32 WGs
  for (int e = mem * 1536 + tid; e < mem * 1536 + 1536; e += BLK) {
    int b = e / 12288, rem = e % 12288, t = rem >> 8, f = rem & 255;
    int gb = gid * 4 + b;
    const float* hs = hist_s + (gb * 48 + t) * 64;
    const float* ha = hist_a + (gb * 48 + t) * 16;
    const float* wsr = Ws + f * 64;
    const float* war = Wa + f * 16;
    float a = bs[f] + ba[f];
    for (int k = 0; k < 64; ++k) a = fmaf(wsr[k], hs[k], a);
    for (int k = 0; k < 16; ++k) a = fmaf(war[k], ha[k], a);
    llc_storef(&seq[(gb * 48 + t) * 256 + f], tanhf(a));
  }
  __syncthreads();

  // ------------- unified loop: u = 0..63 (48 history + 16 rollout) -----------
  // write-once slots: h0r/h1r slot u; no inter-WG barriers needed.
  for (int u = 0; u < 64; ++u) {
    if (isL0) {
      if (u < 48) {
        // history L0: x = seq[:,u,:], h_prev = h0[u-1]
        if (u == 0) {
          poll1(XQ + loff, seq + ((gid * 4 + sb) * 48 + u) * 256 + goff);
          zeroH(HQ + loff);
        } else {
          poll2(XQ + loff, seq + ((gid * 4 + sb) * 48 + u) * 256 + goff,
                HQ + loff, h0r + (u - 1) * 8192 + gvec);
        }
        cell(h0r + u * 8192);
      } else {
        const int t = u - 48;
        if (t == 0) {
          SST[tid] = present_s[(gid * 4 + (tid >> 6)) * 64 + (tid & 63)];
          poll1(HQ + loff, h0r + (u - 1) * 8192 + gvec);
          __syncthreads();
        } else {
          poll2(HQ + loff, h0r + (u - 1) * 8192 + gvec,
                H1Q + loff, h1r + (u - 1) * 8192 + gvec);
          __syncthreads();
          heads(t - 1);
          __syncthreads();
        }
        xdot(t);
        cell(h0r + u * 8192);
      }
    } else {
      // L1: x = h0[u], h_prev = h1[u-1]
      if (u == 0) {
        poll1(XQ + loff, h0r + u * 8192 + gvec);
        zeroH(HQ + loff);
      } else {
        poll2(XQ + loff, h0r + u * 8192 + gvec,
              HQ + loff, h1r + (u - 1) * 8192 + gvec);
      }
      cell(h1r + u * 8192);
    }
  }

  // tail heads for t=15 (mem==0 WG polls h1[63])
  if (isL0 && mem == 0) {
    poll1(H1Q + loff, h1r + 63 * 8192 + gvec);
    __syncthreads();
    heads(15);
  }
}

extern "C" void kernel_launch(void* const* d_in, const int* in_sizes, int n_in,
                              void* d_out, int out_size, void* d_ws, size_t ws_size,
                              hipStream_t stream) {
  (void)in_sizes; (void)n_in; (void)out_size; (void)ws_size;
  const float* hist_s    = (const float*)d_in[0];
  const float* hist_a    = (const float*)d_in[1];
  const float* present_s = (const float*)d_in[2];
  const float* future_a  = (const float*)d_in[3];
  const float* Ws  = (const float*)d_in[4];
  const float* bs  = (const float*)d_in[5];
  const float* Wa  = (const float*)d_in[6];
  const float* ba  = (const float*)d_in[7];
  const float* Wih = (const float*)d_in[8];
  const float* Whh = (const float*)d_in[9];
  const float* bih = (const float*)d_in[10];
  const float* bhh = (const float*)d_in[11];
  const float* Wr  = (const float*)d_in[12];
  const float* br  = (const float*)d_in[13];
  const float* Wso = (const float*)d_in[14];
  const float* bso = (const float*)d_in[15];
  float* out = (float*)d_out;
  float* wsf = (float*)d_ws;

  // poison all cross-WG buffers to sentinel each launch (write-once discipline)
  hipMemsetAsync(d_ws, 0x7F, POISON_BYTES, stream);
  hipFuncSetAttribute(reinterpret_cast<const void*>(gru_rollout_kernel),
                      hipFuncAttributeMaxDynamicSharedMemorySize, LDS_BYTES);
  hipLaunchKernelGGL(gru_rollout_kernel, dim3(256), dim3(BLK), LDS_BYTES, stream,
                     hist_s, hist_a, present_s, future_a,
                     Ws, bs, Wa, ba, Wih, Whh, bih, bhh, Wr, br, Wso, bso,
                     out, wsf);
}